// Round 17
// baseline (118.060 us; speedup 1.0000x reference)
//
#include <hip/hip_runtime.h>

// SelfAttentionHead: B=4, S=4096, D=1024, Hd=128
// wt -> proj v6 (4-buf ring, ONE barrier/iter — race-free: stage target
// (kc+2)%4 never collides at skew<=1 — 4-bank B prefetch, setprio) ->
// attn v17 (8-wave, shared K/V LDS 4-buf ring, ONE barrier/tile, setprio,
// zero-shuffle softmax, key-split x4 same-XCD atomic merge) -> norm

#define BB 4
#define SS 4096
#define DD 1024
#define HDIM 128
#define NTIL 16   // attn: tiles per block (1024 keys / 64)
#define KVB 64    // attn: keys per tile

typedef _Float16 f16;
typedef _Float16 half8 __attribute__((ext_vector_type(8)));
typedef _Float16 half4 __attribute__((ext_vector_type(4)));
typedef __fp16 fp16x2 __attribute__((ext_vector_type(2)));
typedef float f32x4 __attribute__((ext_vector_type(4)));

__device__ __forceinline__ void gload_lds16(const void* g, void* l) {
  __builtin_amdgcn_global_load_lds(
      (const __attribute__((address_space(1))) void*)g,
      (__attribute__((address_space(3))) void*)l, 16, 0, 0);
}

__device__ __forceinline__ f32x4 mfma16(half8 a, half8 b, f32x4 c) {
  return __builtin_amdgcn_mfma_f32_16x16x32_f16(a, b, c, 0, 0, 0);
}

// ---------------------------------------------------------------------------
// Kernel 1: W [1024][128] f32 (x3) -> Wt_cat [384][1024] f16
__global__ void wt_kernel(const float* __restrict__ Wq, const float* __restrict__ Wk,
                          const float* __restrict__ Wv, f16* __restrict__ w3t) {
  const int n = blockIdx.x;  // 0..383
  const float* W = (n < 128) ? Wq : (n < 256) ? Wk : Wv;
  const int col = n & 127;
  for (int d = threadIdx.x; d < DD; d += blockDim.x)
    w3t[(size_t)n * DD + d] = (f16)W[(size_t)d * HDIM + col];
}

// ---------------------------------------------------------------------------
// Kernel 2: projection GEMM v6. 256 blocks x 256 thr (4 waves, 1 block/CU).
// 4-buffer x ring + 4-bank B register prefetch (everything cycles mod 4),
// ONE barrier per K-step. Race-free proof: stage(kc+2)->(kc+2)%4; readers at
// skew 1 use (kc-1)%4 (dist 3) or kc%4 (dist 2); skew>1 impossible (barrier
// kc+1 requires iter-kc reads complete). Own-wave vmcnt retires stage(kc)
// BEFORE barrier kc -> cross-wave LDS visibility holds.
__global__ __launch_bounds__(256)
__attribute__((amdgpu_waves_per_eu(1, 1)))
void proj_kernel(
    const float* __restrict__ x, const f16* __restrict__ w3t,
    f16* __restrict__ Qm, f16* __restrict__ Km, f16* __restrict__ VTm) {
  __shared__ __align__(16) float xa[4][64 * 32];  // 8KB each, swizzled
  const int tid = threadIdx.x;
  const int lane = tid & 63;
  const int wid = tid >> 6;
  const int lo = lane & 15, hi = lane >> 4;
  const int row0 = blockIdx.x * 64;

  auto STAGE = [&](int kc, int bufsel) {
#pragma unroll
    for (int i = 0; i < 2; ++i) {
      const int cid = i * 256 + tid;
      const int r = cid >> 3, c4 = cid & 7;
      gload_lds16((const char*)(x + (size_t)(row0 + r) * DD + kc * 32) +
                      ((c4 * 16) ^ ((r & 7) << 4)),
                  (char*)&xa[bufsel][0] + (size_t)(i * 256 + wid * 64) * 16);
    }
  };

  half8 bf0[6], bf1[6], bf2[6], bf3[6];
  auto BLOAD = [&](half8 (&bf)[6], int kc) {
#pragma unroll
    for (int nf = 0; nf < 6; ++nf) {
      const int n = wid * 96 + nf * 16 + lo;
      bf[nf] = *(const half8*)(w3t + (size_t)n * DD + kc * 32 + hi * 8);
    }
  };

  f32x4 acc[4][6];
#pragma unroll
  for (int m = 0; m < 4; ++m)
#pragma unroll
    for (int nf = 0; nf < 6; ++nf) acc[m][nf] = (f32x4){0.f, 0.f, 0.f, 0.f};

  auto ITER = [&](int kc, int xcb, int xnb, half8 (&bfCur)[6], half8 (&bfN2)[6]) {
    if (kc + 2 < 32) {
      STAGE(kc + 2, xnb);
      asm volatile("s_waitcnt vmcnt(16)" ::: "memory");  // stage(kc) retired
    } else if (kc + 1 < 32) {
      asm volatile("s_waitcnt vmcnt(14)" ::: "memory");
    } else {
      asm volatile("s_waitcnt vmcnt(6)" ::: "memory");
    }
    __builtin_amdgcn_s_barrier();  // sole barrier: tile kc staged everywhere

    if (kc + 2 < 32) BLOAD(bfN2, kc + 2);
    __builtin_amdgcn_sched_barrier(0);  // pin B-prefetch issue early

    const char* xb = (const char*)&xa[xcb][0];
    half8 af[4];
#pragma unroll
    for (int m = 0; m < 4; ++m) {
      const int row = m * 16 + lo;
      const int base = row * 128 + hi * 32;
      const int swz = (row & 7) << 4;
      f32x4 a0 = *(const f32x4*)(xb + (base ^ swz));
      f32x4 a1 = *(const f32x4*)(xb + ((base + 16) ^ swz));
      union { fp16x2 h2[4]; half8 h8; } u;
      u.h2[0] = __builtin_amdgcn_cvt_pkrtz(a0[0], a0[1]);
      u.h2[1] = __builtin_amdgcn_cvt_pkrtz(a0[2], a0[3]);
      u.h2[2] = __builtin_amdgcn_cvt_pkrtz(a1[0], a1[1]);
      u.h2[3] = __builtin_amdgcn_cvt_pkrtz(a1[2], a1[3]);
      af[m] = u.h8;
    }
    __builtin_amdgcn_s_setprio(1);
#pragma unroll
    for (int nf = 0; nf < 6; ++nf)
#pragma unroll
      for (int m = 0; m < 4; ++m)
        acc[m][nf] = mfma16(af[m], bfCur[nf], acc[m][nf]);
    __builtin_amdgcn_s_setprio(0);
    // no trailing barrier: 4-buf ring makes skew-1 writes collision-free
  };

  STAGE(0, 0);
  STAGE(1, 1);
  BLOAD(bf0, 0);
  BLOAD(bf1, 1);
#pragma unroll 1
  for (int g = 0; g < 8; ++g) {
    const int kc = g * 4;
    ITER(kc + 0, 0, 2, bf0, bf2);
    ITER(kc + 1, 1, 3, bf1, bf3);
    ITER(kc + 2, 2, 0, bf2, bf0);
    ITER(kc + 3, 3, 1, bf3, bf1);
  }

  // Epilogue: C lane map row=(l>>4)*4+r, col=l&15; V write key-permuted.
#pragma unroll
  for (int m = 0; m < 4; ++m) {
#pragma unroll
    for (int nf = 0; nf < 6; ++nf) {
      const int n = wid * 96 + nf * 16 + lo;
#pragma unroll
      for (int r = 0; r < 4; ++r) {
        const int row = row0 + m * 16 + hi * 4 + r;
        const f16 v = (f16)acc[m][nf][r];
        if (n < 128) {
          Qm[(size_t)row * HDIM + n] = v;
        } else if (n < 256) {
          Km[(size_t)row * HDIM + (n - 128)] = v;
        } else {
          const int b = row >> 12, s = row & 4095;
          const int t = s & 31;
          const int sp = (s & ~31) | ((t & 0x0C) << 1) | ((t & 0x10) >> 2) | (t & 3);
          VTm[((size_t)b * HDIM + (n - 256)) * SS + sp] = v;
        }
      }
    }
  }
}

// ---------------------------------------------------------------------------
// Kernel 3: fused attention v17. 256 blocks x 512 thr (8 waves, 1 block/CU).
// v15 math + staging; ONE barrier per tile with a 4-buffer ring (128KB LDS):
// stage(kt+2)->(kt+2)%4 vs readers (kt-1)%4 / kt%4 = distance 3 / 2, and
// skew>1 impossible. Own-wave vmcnt(8) retires stage(kt) before barrier kt.
// setprio(1) around MFMA clusters (waves de-lockstep -> role diversity).
__global__ __launch_bounds__(512)
__attribute__((amdgpu_waves_per_eu(2, 2)))
void attn_kernel(
    const f16* __restrict__ Qm, const f16* __restrict__ Km,
    const f16* __restrict__ VTm, float* __restrict__ out,
    float* __restrict__ lws) {
  __shared__ __align__(16) f16 Kt[4][KVB * 128];  // 64KB
  __shared__ __align__(16) f16 Vt[4][128 * KVB];  // 64KB

  // Same-XCD split map: all 4 key-splits of one (b,qt) on one XCD
  const int xcd = blockIdx.x & 7;
  const int i = blockIdx.x >> 3;  // 0..31
  const int b = xcd >> 1;
  const int qt = (i & 7) * 2 + (xcd & 1);
  const int split = i >> 3;
  const int tid = threadIdx.x;
  const int wid = tid >> 6;
  const int lane = tid & 63;
  const int lo = lane & 15, hi = lane >> 4;
  const int q0 = qt * 256 + wid * 32;
  const int kbase = split * (NTIL * KVB);

  constexpr float SCL2E = 0.12751744560817508f;  // log2(e)/sqrt(128)

  half8 qf[2][4];
#pragma unroll
  for (int m = 0; m < 2; ++m)
#pragma unroll
    for (int c = 0; c < 4; ++c) {
      half8 q = *(const half8*)(Qm + (size_t)(b * SS + q0 + m * 16 + lo) * HDIM +
                                c * 32 + hi * 8);
#pragma unroll
      for (int j = 0; j < 8; ++j) q[j] = (f16)((float)q[j] * SCL2E);
      qf[m][c] = q;
    }

  f32x4 of[2][8];
#pragma unroll
  for (int m = 0; m < 2; ++m)
#pragma unroll
    for (int g2 = 0; g2 < 8; ++g2) of[m][g2] = (f32x4){0.f, 0.f, 0.f, 0.f};
  float lrun[2] = {0.f, 0.f};

  const char* kgb = (const char*)(Km + ((size_t)b * SS + kbase) * HDIM);
  const char* vgb = (const char*)(VTm + (size_t)b * HDIM * SS) + (size_t)kbase * 2;

  auto STAGE = [&](int kt2, int bufsel) {
    char* kd = (char*)&Kt[bufsel][0];
    char* vd = (char*)&Vt[bufsel][0];
#pragma unroll
    for (int i2 = 0; i2 < 2; ++i2) {
      const int cid = i2 * 512 + tid;
      const int r = cid >> 4, c4 = cid & 15;
      gload_lds16(kgb + (size_t)(kt2 * KVB + r) * 256 + ((c4 * 16) ^ ((r & 7) << 4)),
                  kd + (size_t)(i2 * 512 + wid * 64) * 16);
    }
#pragma unroll
    for (int i2 = 0; i2 < 2; ++i2) {
      const int cid = i2 * 512 + tid;
      const int r = cid >> 3, c8 = cid & 7;
      gload_lds16(vgb + (size_t)r * (SS * 2) + (size_t)(kt2 * KVB) * 2 +
                      ((c8 * 16) ^ ((r & 7) << 4)),
                  vd + (size_t)(i2 * 512 + wid * 64) * 16);
    }
  };

  auto ITER = [&](int kt, int cb, int nb) {
    if (kt + 2 < NTIL) {
      STAGE(kt + 2, nb);
      asm volatile("s_waitcnt vmcnt(8)" ::: "memory");  // stage(kt) retired
    } else if (kt + 1 < NTIL) {
      asm volatile("s_waitcnt vmcnt(4)" ::: "memory");
    } else {
      asm volatile("s_waitcnt vmcnt(0)" ::: "memory");
    }
    __builtin_amdgcn_s_barrier();  // sole barrier: tile kt staged everywhere

    const char* KtC = (const char*)&Kt[cb][0];
    const char* VtC = (const char*)&Vt[cb][0];

    f32x4 sc[2][4];
#pragma unroll
    for (int m = 0; m < 2; ++m)
#pragma unroll
      for (int g = 0; g < 4; ++g) sc[m][g] = (f32x4){0.f, 0.f, 0.f, 0.f};
    __builtin_amdgcn_s_setprio(1);
#pragma unroll
    for (int c = 0; c < 4; ++c)
#pragma unroll
      for (int g = 0; g < 4; ++g) {
        const int row = g * 16 + lo;
        const half8 kb = *(const half8*)(KtC + row * 256 +
                                         ((c * 64 + hi * 16) ^ ((row & 7) << 4)));
        sc[0][g] = mfma16(kb, qf[0][c], sc[0][g]);
        sc[1][g] = mfma16(kb, qf[1][c], sc[1][g]);
      }
    __builtin_amdgcn_s_setprio(0);

    half8 pa[2][2];
#pragma unroll
    for (int m = 0; m < 2; ++m) {
#pragma unroll
      for (int kc = 0; kc < 2; ++kc) {
        union { half4 h4[2]; half8 h8; } pu;
#pragma unroll
        for (int gg = 0; gg < 2; ++gg) {
          const int g = kc * 2 + gg;
          const float p0 = __builtin_amdgcn_exp2f(sc[m][g][0]);
          const float p1 = __builtin_amdgcn_exp2f(sc[m][g][1]);
          const float p2 = __builtin_amdgcn_exp2f(sc[m][g][2]);
          const float p3 = __builtin_amdgcn_exp2f(sc[m][g][3]);
          union { fp16x2 h2[2]; half4 h4; } u;
          u.h2[0] = __builtin_amdgcn_cvt_pkrtz(p0, p1);
          u.h2[1] = __builtin_amdgcn_cvt_pkrtz(p2, p3);
          pu.h4[gg] = u.h4;
          lrun[m] += (p0 + p1) + (p2 + p3);
        }
        pa[m][kc] = pu.h8;
      }
    }

    __builtin_amdgcn_s_setprio(1);
#pragma unroll
    for (int kc = 0; kc < 2; ++kc)
#pragma unroll
      for (int g2 = 0; g2 < 8; ++g2) {
        const int row = g2 * 16 + lo;
        const half8 vb = *(const half8*)(VtC + row * 128 +
                                         ((kc * 64 + hi * 16) ^ ((row & 7) << 4)));
        of[0][g2] = mfma16(pa[0][kc], vb, of[0][g2]);
        of[1][g2] = mfma16(pa[1][kc], vb, of[1][g2]);
      }
    __builtin_amdgcn_s_setprio(0);
    // no trailing barrier: 4-buf ring makes skew-1 writes collision-free
  };

  STAGE(0, 0);
  STAGE(1, 1);
#pragma unroll 1
  for (int g = 0; g < 4; ++g) {
    const int kt = g * 4;
    ITER(kt + 0, 0, 2);
    ITER(kt + 1, 1, 3);
    ITER(kt + 2, 2, 0);
    ITER(kt + 3, 3, 1);
  }

  // ---- epilogue: finish l-reduce, atomic merge (same-XCD L2-local)
#pragma unroll
  for (int m = 0; m < 2; ++m) {
    lrun[m] += __shfl_xor(lrun[m], 16, 64);
    lrun[m] += __shfl_xor(lrun[m], 32, 64);
  }

  float* op = out + ((size_t)(b * SS + q0)) * HDIM;
#pragma unroll
  for (int m = 0; m < 2; ++m) {
#pragma unroll
    for (int r = 0; r < 4; ++r) {
      const int row = m * 16 + hi * 4 + r;
#pragma unroll
      for (int g2 = 0; g2 < 8; ++g2)
        atomicAdd(&op[(size_t)row * HDIM + g2 * 16 + lo], of[m][g2][r]);
    }
  }
  if (hi == 0) {
    atomicAdd(&lws[b * SS + q0 + lo], lrun[0]);
    atomicAdd(&lws[b * SS + q0 + 16 + lo], lrun[1]);
  }
}

// ---------------------------------------------------------------------------
// Kernel 4: normalize out by row-sum l. 2048 blocks x 256 thr, f32x4 each.
__global__ void norm_kernel(float* __restrict__ out, const float* __restrict__ lws) {
  const int idx = blockIdx.x * 256 + threadIdx.x;  // f32x4 index; 32 per row
  f32x4 v = ((const f32x4*)out)[idx];
  const float inv = 1.0f / lws[idx >> 5];
  v[0] *= inv; v[1] *= inv; v[2] *= inv; v[3] *= inv;
  ((f32x4*)out)[idx] = v;
}

// ---------------------------------------------------------------------------
extern "C" void kernel_launch(void* const* d_in, const int* in_sizes, int n_in,
                              void* d_out, int out_size, void* d_ws, size_t ws_size,
                              hipStream_t stream) {
  (void)in_sizes; (void)n_in; (void)out_size; (void)ws_size;
  const float* x  = (const float*)d_in[0];
  const float* Wq = (const float*)d_in[1];
  const float* Wk = (const float*)d_in[2];
  const float* Wv = (const float*)d_in[3];
  float* out = (float*)d_out;

  f16* Qm  = (f16*)d_ws;
  f16* Km  = Qm + (size_t)BB * SS * HDIM;
  f16* VTm = Km + (size_t)BB * SS * HDIM;
  f16* W3  = VTm + (size_t)BB * SS * HDIM;
  float* lws = (float*)(W3 + (size_t)384 * DD);  // 16384 f32 = 64KB

  hipMemsetAsync(out, 0, (size_t)BB * SS * HDIM * sizeof(float), stream);
  hipMemsetAsync(lws, 0, (size_t)BB * SS * sizeof(float), stream);

  hipLaunchKernelGGL(wt_kernel, dim3(384), dim3(256), 0, stream, Wq, Wk, Wv, W3);
  hipLaunchKernelGGL(proj_kernel, dim3(256), dim3(256), 0, stream, x, W3, Qm, Km, VTm);
  hipLaunchKernelGGL(attn_kernel, dim3(256), dim3(512), 0, stream, Qm, Km, VTm, out, lws);
  hipLaunchKernelGGL(norm_kernel, dim3(2048), dim3(256), 0, stream, out, lws);
}

// Round 18
// 112.672 us; speedup vs baseline: 1.0478x; 1.0478x over previous
//
#include <hip/hip_runtime.h>

// SelfAttentionHead: B=4, S=4096, D=1024, Hd=128
// FINAL (revert to round-15 best, 112.56us):
// wt -> proj v4 (64-row blocks; x 3-buf staged; B-frags 2-deep reg prefetch)
// -> attn v15 (8-wave blocks, shared K/V LDS tiles, 3-buf 2-deep staging,
// zero-shuffle softmax, key-split x4 w/ SAME-XCD atomic merge) -> norm

#define BB 4
#define SS 4096
#define DD 1024
#define HDIM 128
#define NTIL 16   // attn: tiles per block (1024 keys / 64)
#define KVB 64    // attn: keys per tile

typedef _Float16 f16;
typedef _Float16 half8 __attribute__((ext_vector_type(8)));
typedef _Float16 half4 __attribute__((ext_vector_type(4)));
typedef __fp16 fp16x2 __attribute__((ext_vector_type(2)));
typedef float f32x4 __attribute__((ext_vector_type(4)));

__device__ __forceinline__ void gload_lds16(const void* g, void* l) {
  __builtin_amdgcn_global_load_lds(
      (const __attribute__((address_space(1))) void*)g,
      (__attribute__((address_space(3))) void*)l, 16, 0, 0);
}

__device__ __forceinline__ f32x4 mfma16(half8 a, half8 b, f32x4 c) {
  return __builtin_amdgcn_mfma_f32_16x16x32_f16(a, b, c, 0, 0, 0);
}

// ---------------------------------------------------------------------------
// Kernel 1: W [1024][128] f32 (x3) -> Wt_cat [384][1024] f16
__global__ void wt_kernel(const float* __restrict__ Wq, const float* __restrict__ Wk,
                          const float* __restrict__ Wv, f16* __restrict__ w3t) {
  const int n = blockIdx.x;  // 0..383
  const float* W = (n < 128) ? Wq : (n < 256) ? Wk : Wv;
  const int col = n & 127;
  for (int d = threadIdx.x; d < DD; d += blockDim.x)
    w3t[(size_t)n * DD + d] = (f16)W[(size_t)d * HDIM + col];
}

// ---------------------------------------------------------------------------
// Kernel 2: projection GEMM v4. 256 blocks x 256 thr (4 waves, 1 block/CU).
// Block = 64 rows; wave = 64 rows x 96 cols. x staged in a 3-buffer LDS ring
// (1-deep wait, 2 tiles in flight); B-frags in 3 register banks loaded 2
// tiles ahead. vmcnt counts from exact in-order FIFO: 16 / 14 / 6.
__global__ __launch_bounds__(256)
__attribute__((amdgpu_waves_per_eu(1, 1)))
void proj_kernel(
    const float* __restrict__ x, const f16* __restrict__ w3t,
    f16* __restrict__ Qm, f16* __restrict__ Km, f16* __restrict__ VTm) {
  __shared__ __align__(16) float xa[3][64 * 32];  // 8KB each, swizzled
  const int tid = threadIdx.x;
  const int lane = tid & 63;
  const int wid = tid >> 6;
  const int lo = lane & 15, hi = lane >> 4;
  const int row0 = blockIdx.x * 64;

  auto STAGE = [&](int kc, int bufsel) {
#pragma unroll
    for (int i = 0; i < 2; ++i) {
      const int cid = i * 256 + tid;
      const int r = cid >> 3, c4 = cid & 7;
      gload_lds16((const char*)(x + (size_t)(row0 + r) * DD + kc * 32) +
                      ((c4 * 16) ^ ((r & 7) << 4)),
                  (char*)&xa[bufsel][0] + (size_t)(i * 256 + wid * 64) * 16);
    }
  };

  half8 bf0[6], bf1[6], bf2[6];
  auto BLOAD = [&](half8 (&bf)[6], int kc) {
#pragma unroll
    for (int nf = 0; nf < 6; ++nf) {
      const int n = wid * 96 + nf * 16 + lo;
      bf[nf] = *(const half8*)(w3t + (size_t)n * DD + kc * 32 + hi * 8);
    }
  };

  f32x4 acc[4][6];
#pragma unroll
  for (int m = 0; m < 4; ++m)
#pragma unroll
    for (int nf = 0; nf < 6; ++nf) acc[m][nf] = (f32x4){0.f, 0.f, 0.f, 0.f};

  auto ITER = [&](int kc, int xcb, int xnb, half8 (&bfCur)[6], half8 (&bfN2)[6]) {
    if (kc + 2 < 32) {
      STAGE(kc + 2, xnb);
      asm volatile("s_waitcnt vmcnt(16)" ::: "memory");  // stage(kc) retired
    } else if (kc + 1 < 32) {
      asm volatile("s_waitcnt vmcnt(14)" ::: "memory");
    } else {
      asm volatile("s_waitcnt vmcnt(6)" ::: "memory");
    }
    __builtin_amdgcn_s_barrier();

    if (kc + 2 < 32) BLOAD(bfN2, kc + 2);
    __builtin_amdgcn_sched_barrier(0);  // pin B-prefetch issue early

    const char* xb = (const char*)&xa[xcb][0];
    half8 af[4];
#pragma unroll
    for (int m = 0; m < 4; ++m) {
      const int row = m * 16 + lo;
      const int base = row * 128 + hi * 32;
      const int swz = (row & 7) << 4;
      f32x4 a0 = *(const f32x4*)(xb + (base ^ swz));
      f32x4 a1 = *(const f32x4*)(xb + ((base + 16) ^ swz));
      union { fp16x2 h2[4]; half8 h8; } u;
      u.h2[0] = __builtin_amdgcn_cvt_pkrtz(a0[0], a0[1]);
      u.h2[1] = __builtin_amdgcn_cvt_pkrtz(a0[2], a0[3]);
      u.h2[2] = __builtin_amdgcn_cvt_pkrtz(a1[0], a1[1]);
      u.h2[3] = __builtin_amdgcn_cvt_pkrtz(a1[2], a1[3]);
      af[m] = u.h8;
    }
#pragma unroll
    for (int nf = 0; nf < 6; ++nf)
#pragma unroll
      for (int m = 0; m < 4; ++m)
        acc[m][nf] = mfma16(af[m], bfCur[nf], acc[m][nf]);

    __builtin_amdgcn_s_barrier();
  };

  STAGE(0, 0);
  STAGE(1, 1);
  BLOAD(bf0, 0);
  BLOAD(bf1, 1);
#pragma unroll 1
  for (int g = 0; g < 10; ++g) {
    const int kc = g * 3;
    ITER(kc + 0, 0, 2, bf0, bf2);
    ITER(kc + 1, 1, 0, bf1, bf0);
    ITER(kc + 2, 2, 1, bf2, bf1);
  }
  ITER(30, 0, 2, bf0, bf2);
  ITER(31, 1, 0, bf1, bf0);

  // Epilogue: C lane map row=(l>>4)*4+r, col=l&15; V write key-permuted.
#pragma unroll
  for (int m = 0; m < 4; ++m) {
#pragma unroll
    for (int nf = 0; nf < 6; ++nf) {
      const int n = wid * 96 + nf * 16 + lo;
#pragma unroll
      for (int r = 0; r < 4; ++r) {
        const int row = row0 + m * 16 + hi * 4 + r;
        const f16 v = (f16)acc[m][nf][r];
        if (n < 128) {
          Qm[(size_t)row * HDIM + n] = v;
        } else if (n < 256) {
          Km[(size_t)row * HDIM + (n - 128)] = v;
        } else {
          const int b = row >> 12, s = row & 4095;
          const int t = s & 31;
          const int sp = (s & ~31) | ((t & 0x0C) << 1) | ((t & 0x10) >> 2) | (t & 3);
          VTm[((size_t)b * HDIM + (n - 256)) * SS + sp] = v;
        }
      }
    }
  }
}

// ---------------------------------------------------------------------------
// Kernel 3: fused attention v15. 256 blocks x 512 thr (8 waves, 1 block/CU).
// Shared K/V LDS tiles (3-buffer, 2-deep staging, vmcnt 8/4/0); XCD map puts
// all 4 key-splits of one (b,qt) on the SAME XCD so the atomic merge is
// L2-local. Zero-shuffle softmax (V key-permuted); atomic merge + norm.
__global__ __launch_bounds__(512)
__attribute__((amdgpu_waves_per_eu(2, 2)))
void attn_kernel(
    const f16* __restrict__ Qm, const f16* __restrict__ Km,
    const f16* __restrict__ VTm, float* __restrict__ out,
    float* __restrict__ lws) {
  __shared__ __align__(16) f16 Kt[3][KVB * 128];  // 48KB
  __shared__ __align__(16) f16 Vt[3][128 * KVB];  // 48KB

  // Same-XCD split map: b=xcd>>1, qt=(i&7)*2+(xcd&1), split=i>>3
  const int xcd = blockIdx.x & 7;
  const int i = blockIdx.x >> 3;  // 0..31
  const int b = xcd >> 1;
  const int qt = (i & 7) * 2 + (xcd & 1);
  const int split = i >> 3;
  const int tid = threadIdx.x;
  const int wid = tid >> 6;
  const int lane = tid & 63;
  const int lo = lane & 15, hi = lane >> 4;
  const int q0 = qt * 256 + wid * 32;
  const int kbase = split * (NTIL * KVB);

  constexpr float SCL2E = 0.12751744560817508f;  // log2(e)/sqrt(128)

  half8 qf[2][4];
#pragma unroll
  for (int m = 0; m < 2; ++m)
#pragma unroll
    for (int c = 0; c < 4; ++c) {
      half8 q = *(const half8*)(Qm + (size_t)(b * SS + q0 + m * 16 + lo) * HDIM +
                                c * 32 + hi * 8);
#pragma unroll
      for (int j = 0; j < 8; ++j) q[j] = (f16)((float)q[j] * SCL2E);
      qf[m][c] = q;
    }

  f32x4 of[2][8];
#pragma unroll
  for (int m = 0; m < 2; ++m)
#pragma unroll
    for (int g2 = 0; g2 < 8; ++g2) of[m][g2] = (f32x4){0.f, 0.f, 0.f, 0.f};
  float lrun[2] = {0.f, 0.f};

  const char* kgb = (const char*)(Km + ((size_t)b * SS + kbase) * HDIM);
  const char* vgb = (const char*)(VTm + (size_t)b * HDIM * SS) + (size_t)kbase * 2;

  auto STAGE = [&](int kt2, int bufsel) {
    char* kd = (char*)&Kt[bufsel][0];
    char* vd = (char*)&Vt[bufsel][0];
#pragma unroll
    for (int i2 = 0; i2 < 2; ++i2) {
      const int cid = i2 * 512 + tid;
      const int r = cid >> 4, c4 = cid & 15;
      gload_lds16(kgb + (size_t)(kt2 * KVB + r) * 256 + ((c4 * 16) ^ ((r & 7) << 4)),
                  kd + (size_t)(i2 * 512 + wid * 64) * 16);
    }
#pragma unroll
    for (int i2 = 0; i2 < 2; ++i2) {
      const int cid = i2 * 512 + tid;
      const int r = cid >> 3, c8 = cid & 7;
      gload_lds16(vgb + (size_t)r * (SS * 2) + (size_t)(kt2 * KVB) * 2 +
                      ((c8 * 16) ^ ((r & 7) << 4)),
                  vd + (size_t)(i2 * 512 + wid * 64) * 16);
    }
  };

  auto ITER = [&](int kt, int cb, int nb) {
    if (kt + 2 < NTIL) {
      STAGE(kt + 2, nb);
      asm volatile("s_waitcnt vmcnt(8)" ::: "memory");  // stage(kt) retired
    } else if (kt + 1 < NTIL) {
      asm volatile("s_waitcnt vmcnt(4)" ::: "memory");
    } else {
      asm volatile("s_waitcnt vmcnt(0)" ::: "memory");
    }
    __builtin_amdgcn_s_barrier();

    const char* KtC = (const char*)&Kt[cb][0];
    const char* VtC = (const char*)&Vt[cb][0];

    f32x4 sc[2][4];
#pragma unroll
    for (int m = 0; m < 2; ++m)
#pragma unroll
      for (int g = 0; g < 4; ++g) sc[m][g] = (f32x4){0.f, 0.f, 0.f, 0.f};
#pragma unroll
    for (int c = 0; c < 4; ++c)
#pragma unroll
      for (int g = 0; g < 4; ++g) {
        const int row = g * 16 + lo;
        const half8 kb = *(const half8*)(KtC + row * 256 +
                                         ((c * 64 + hi * 16) ^ ((row & 7) << 4)));
        sc[0][g] = mfma16(kb, qf[0][c], sc[0][g]);
        sc[1][g] = mfma16(kb, qf[1][c], sc[1][g]);
      }

    half8 pa[2][2];
#pragma unroll
    for (int m = 0; m < 2; ++m) {
#pragma unroll
      for (int kc = 0; kc < 2; ++kc) {
        union { half4 h4[2]; half8 h8; } pu;
#pragma unroll
        for (int gg = 0; gg < 2; ++gg) {
          const int g = kc * 2 + gg;
          const float p0 = __builtin_amdgcn_exp2f(sc[m][g][0]);
          const float p1 = __builtin_amdgcn_exp2f(sc[m][g][1]);
          const float p2 = __builtin_amdgcn_exp2f(sc[m][g][2]);
          const float p3 = __builtin_amdgcn_exp2f(sc[m][g][3]);
          union { fp16x2 h2[2]; half4 h4; } u;
          u.h2[0] = __builtin_amdgcn_cvt_pkrtz(p0, p1);
          u.h2[1] = __builtin_amdgcn_cvt_pkrtz(p2, p3);
          pu.h4[gg] = u.h4;
          lrun[m] += (p0 + p1) + (p2 + p3);
        }
        pa[m][kc] = pu.h8;
      }
    }

#pragma unroll
    for (int kc = 0; kc < 2; ++kc)
#pragma unroll
      for (int g2 = 0; g2 < 8; ++g2) {
        const int row = g2 * 16 + lo;
        const half8 vb = *(const half8*)(VtC + row * 128 +
                                         ((kc * 64 + hi * 16) ^ ((row & 7) << 4)));
        of[0][g2] = mfma16(pa[0][kc], vb, of[0][g2]);
        of[1][g2] = mfma16(pa[1][kc], vb, of[1][g2]);
      }

    __builtin_amdgcn_s_barrier();
  };

  STAGE(0, 0);
  STAGE(1, 1);
#pragma unroll 1
  for (int g = 0; g < 5; ++g) {
    const int kt = g * 3;
    ITER(kt + 0, 0, 2);
    ITER(kt + 1, 1, 0);
    ITER(kt + 2, 2, 1);
  }
  ITER(15, 0, 2);

  // ---- epilogue: finish l-reduce, atomic merge (same-XCD L2-local)
#pragma unroll
  for (int m = 0; m < 2; ++m) {
    lrun[m] += __shfl_xor(lrun[m], 16, 64);
    lrun[m] += __shfl_xor(lrun[m], 32, 64);
  }

  float* op = out + ((size_t)(b * SS + q0)) * HDIM;
#pragma unroll
  for (int m = 0; m < 2; ++m) {
#pragma unroll
    for (int r = 0; r < 4; ++r) {
      const int row = m * 16 + hi * 4 + r;
#pragma unroll
      for (int g2 = 0; g2 < 8; ++g2)
        atomicAdd(&op[(size_t)row * HDIM + g2 * 16 + lo], of[m][g2][r]);
    }
  }
  if (hi == 0) {
    atomicAdd(&lws[b * SS + q0 + lo], lrun[0]);
    atomicAdd(&lws[b * SS + q0 + 16 + lo], lrun[1]);
  }
}

// ---------------------------------------------------------------------------
// Kernel 4: normalize out by row-sum l. 2048 blocks x 256 thr, f32x4 each.
__global__ void norm_kernel(float* __restrict__ out, const float* __restrict__ lws) {
  const int idx = blockIdx.x * 256 + threadIdx.x;  // f32x4 index; 32 per row
  f32x4 v = ((const f32x4*)out)[idx];
  const float inv = 1.0f / lws[idx >> 5];
  v[0] *= inv; v[1] *= inv; v[2] *= inv; v[3] *= inv;
  ((f32x4*)out)[idx] = v;
}

// ---------------------------------------------------------------------------
extern "C" void kernel_launch(void* const* d_in, const int* in_sizes, int n_in,
                              void* d_out, int out_size, void* d_ws, size_t ws_size,
                              hipStream_t stream) {
  (void)in_sizes; (void)n_in; (void)out_size; (void)ws_size;
  const float* x  = (const float*)d_in[0];
  const float* Wq = (const float*)d_in[1];
  const float* Wk = (const float*)d_in[2];
  const float* Wv = (const float*)d_in[3];
  float* out = (float*)d_out;

  f16* Qm  = (f16*)d_ws;
  f16* Km  = Qm + (size_t)BB * SS * HDIM;
  f16* VTm = Km + (size_t)BB * SS * HDIM;
  f16* W3  = VTm + (size_t)BB * SS * HDIM;
  float* lws = (float*)(W3 + (size_t)384 * DD);  // 16384 f32 = 64KB

  hipMemsetAsync(out, 0, (size_t)BB * SS * HDIM * sizeof(float), stream);
  hipMemsetAsync(lws, 0, (size_t)BB * SS * sizeof(float), stream);

  hipLaunchKernelGGL(wt_kernel, dim3(384), dim3(256), 0, stream, Wq, Wk, Wv, W3);
  hipLaunchKernelGGL(proj_kernel, dim3(256), dim3(256), 0, stream, x, W3, Qm, Km, VTm);
  hipLaunchKernelGGL(attn_kernel, dim3(256), dim3(512), 0, stream, Qm, Km, VTm, out, lws);
  hipLaunchKernelGGL(norm_kernel, dim3(2048), dim3(256), 0, stream, out, lws);
}